// Round 13
// baseline (218.419 us; speedup 1.0000x reference)
//
#include <hip/hip_runtime.h>
#include <math.h>

// Problem constants (from reference)
#define Bn   16
#define Cn   64
#define Nn   65536        // H*W = 256*256
#define Sn   64           // n-slices per batch for gram kernel
#define Ln   (Nn / Sn)    // 1024 k-elements per block (256 per wave)
#define REDn 16

typedef float    f32x4  __attribute__((ext_vector_type(4)));
typedef float    f32x16 __attribute__((ext_vector_type(16)));
typedef __fp16   fp16x2 __attribute__((ext_vector_type(2)));
typedef _Float16 f16x8  __attribute__((ext_vector_type(8)));

union half8_u {
  f16x8  v;
  fp16x2 h[4];
};

// ---------------------------------------------------------------------------
// ABLATION ROUND: identical to R12 except gram_pool_kernel is launched TWICE
// (idempotent). Total-time delta vs R12 (153.9us) == gram's true duration.
// ---------------------------------------------------------------------------
__global__ __launch_bounds__(256, 4) void gram_pool_kernel(
    const float* __restrict__ x, const float* __restrict__ Wrow,
    float* __restrict__ part) {
  const int b    = blockIdx.x / Sn;
  const int s    = blockIdx.x % Sn;
  const int tid  = threadIdx.x;
  const int wid  = tid >> 6;
  const int lane = tid & 63;
  const int l31  = lane & 31;
  const int lhi  = lane >> 5;
  const int rr   = lane >> 2;   // staging row-within-group (0..15)
  const int cc   = lane & 3;    // staging 16B chunk (0..3)

  const float* xb = x + (size_t)b * Cn * Nn;

  __shared__ float stage[4][Cn * 17];   // per-wave [64 rows][17] f32 (pad)
  __shared__ float corr_s[Cn][Cn + 1];
  __shared__ float pool_lds0[4][32];
  __shared__ float pool_lds1[4][32];

  float* wb = &stage[wid][0];

  const float* gsrc[4];
  int widx[4];
#pragma unroll
  for (int i = 0; i < 4; ++i) {
    const int row = 16 * i + rr;
    gsrc[i] = xb + (size_t)row * Nn + cc * 4;
    widx[i] = row * 17 + cc * 4;
  }
  const int fA = l31 * 17 + lhi * 8;          // rows 0..31
  const int fB = (l31 + 32) * 17 + lhi * 8;   // rows 32..63

  const int kw = s * Ln + wid * (Ln / 4);     // wave's k base; 16 tiles of 16

  f32x16 acc00, acc01, acc11;
#pragma unroll
  for (int r = 0; r < 16; ++r) { acc00[r] = 0.f; acc01[r] = 0.f; acc11[r] = 0.f; }
  float pool0 = 0.f, pool1 = 0.f;
  const fp16x2 one2 = {(__fp16)1.0f, (__fp16)1.0f};

  // register prefetch pipeline, 3 tiles deep
  f32x4 sA[4], sB[4], sC[4];
#pragma unroll
  for (int i = 0; i < 4; ++i) sA[i] = *(const f32x4*)(gsrc[i] + kw);
#pragma unroll
  for (int i = 0; i < 4; ++i) sB[i] = *(const f32x4*)(gsrc[i] + kw + 16);
#pragma unroll
  for (int i = 0; i < 4; ++i) sC[i] = *(const f32x4*)(gsrc[i] + kw + 32);

  auto step = [&](f32x4* stg, int t) {
#pragma unroll
    for (int i = 0; i < 4; ++i) *(f32x4*)&wb[widx[i]] = stg[i];
    if (t < 13) {
      const int ko = kw + (t + 3) * 16;
#pragma unroll
      for (int i = 0; i < 4; ++i) stg[i] = *(const f32x4*)(gsrc[i] + ko);
    }
    f32x4 a0 = *(const f32x4*)&wb[fA];
    f32x4 a1 = *(const f32x4*)&wb[fA + 4];
    f32x4 c0 = *(const f32x4*)&wb[fB];
    f32x4 c1 = *(const f32x4*)&wb[fB + 4];

    half8_u au, bu;
    au.h[0] = __builtin_amdgcn_cvt_pkrtz(a0[0], a0[1]);
    au.h[1] = __builtin_amdgcn_cvt_pkrtz(a0[2], a0[3]);
    au.h[2] = __builtin_amdgcn_cvt_pkrtz(a1[0], a1[1]);
    au.h[3] = __builtin_amdgcn_cvt_pkrtz(a1[2], a1[3]);
    bu.h[0] = __builtin_amdgcn_cvt_pkrtz(c0[0], c0[1]);
    bu.h[1] = __builtin_amdgcn_cvt_pkrtz(c0[2], c0[3]);
    bu.h[2] = __builtin_amdgcn_cvt_pkrtz(c1[0], c1[1]);
    bu.h[3] = __builtin_amdgcn_cvt_pkrtz(c1[2], c1[3]);

#pragma unroll
    for (int i = 0; i < 4; ++i) {
      pool0 = __builtin_amdgcn_fdot2(au.h[i], one2, pool0, false);
      pool1 = __builtin_amdgcn_fdot2(bu.h[i], one2, pool1, false);
    }

    acc00 = __builtin_amdgcn_mfma_f32_32x32x16_f16(au.v, au.v, acc00, 0, 0, 0);
    acc01 = __builtin_amdgcn_mfma_f32_32x32x16_f16(au.v, bu.v, acc01, 0, 0, 0);
    acc11 = __builtin_amdgcn_mfma_f32_32x32x16_f16(bu.v, bu.v, acc11, 0, 0, 0);
  };

#pragma unroll
  for (int tp = 0; tp < 5; ++tp) {
    step(sA, 3 * tp);
    step(sB, 3 * tp + 1);
    step(sC, 3 * tp + 2);
  }
  step(sA, 15);

  pool0 += __shfl_down(pool0, 32);
  pool1 += __shfl_down(pool1, 32);
  if (lane < 32) {
    pool_lds0[wid][lane] = pool0;
    pool_lds1[wid][lane] = pool1;
  }

  for (int w = 0; w < 4; ++w) {
    __syncthreads();
    if (wid == w) {
#pragma unroll
      for (int r = 0; r < 16; ++r) {
        // verified C/D layout (32x32 MFMA): col=lane&31, row=(r&3)+8*(r>>2)+4*(lane>>5)
        const int i = (r & 3) + 8 * (r >> 2) + 4 * lhi;
        const int j = l31;
        if (w == 0) {
          corr_s[i][j]           = acc00[r];
          corr_s[i][j + 32]      = acc01[r];
          corr_s[j + 32][i]      = acc01[r];   // symmetric mirror
          corr_s[i + 32][j + 32] = acc11[r];
        } else {
          corr_s[i][j]           += acc00[r];
          corr_s[i][j + 32]      += acc01[r];
          corr_s[j + 32][i]      += acc01[r];
          corr_s[i + 32][j + 32] += acc11[r];
        }
      }
    }
  }
  __syncthreads();

  if (tid < Cn) {
    const float* wr = Wrow + tid * Cn;
    float so = 0.f;
#pragma unroll 8
    for (int d = 0; d < Cn; ++d) so += corr_s[tid][d] * wr[d];
    float pp = 0.f;
    if (tid < 32) {
#pragma unroll
      for (int w = 0; w < 4; ++w) pp += pool_lds0[w][tid];
    } else {
#pragma unroll
      for (int w = 0; w < 4; ++w) pp += pool_lds1[w][tid - 32];
    }
    float* o = part + (size_t)(b * Sn + s) * (2 * Cn);
    o[tid]      = so;
    o[Cn + tid] = pp;
  }
}

// ---------------------------------------------------------------------------
// Kernel 2: per-batch reduce partials + tiny MLP -> gate g[b,c]
// ---------------------------------------------------------------------------
__global__ __launch_bounds__(64) void se_kernel(
    const float* __restrict__ part, const float* __restrict__ brow,
    const float* __restrict__ W1, const float* __restrict__ b1,
    const float* __restrict__ W2, const float* __restrict__ b2,
    float* __restrict__ g) {
  const int b = blockIdx.x;
  const int t = threadIdx.x;   // 0..63

  __shared__ float y_s[Cn];
  __shared__ float z_s[REDn];

  float so = 0.f, pl = 0.f;
  for (int s = 0; s < Sn; ++s) {
    const float* p = part + (size_t)(b * Sn + s) * (2 * Cn);
    so += p[t];
    pl += p[Cn + t];
  }
  y_s[t] = (so + pl) * (1.0f / (float)Nn) + brow[t];
  __syncthreads();

  if (t < REDn) {
    float z = b1[t];
#pragma unroll 8
    for (int c = 0; c < Cn; ++c) z += W1[t * Cn + c] * y_s[c];
    z_s[t] = fmaxf(z, 0.f);
  }
  __syncthreads();

  float a = b2[t];
#pragma unroll
  for (int r = 0; r < REDn; ++r) a += W2[t * REDn + r] * z_s[r];
  g[b * Cn + t] = 1.0f / (1.0f + expf(-a));
}

// ---------------------------------------------------------------------------
// Kernel 3: out[b,c,n] = x[b,c,n] * g[b,c]  (contiguous per-plane blocks, NT)
// ---------------------------------------------------------------------------
#define SGRID 4096        // 16384 float4 per (b,c) / 4096 per block = 4 blocks/plane
__global__ __launch_bounds__(256) void scale_kernel(
    const float* __restrict__ x, const float* __restrict__ g,
    float* __restrict__ out) {
  const int    bid   = blockIdx.x;
  const size_t base4 = (size_t)bid * 4096;   // float4 index of block's region
  const float  gg    = g[bid >> 2];          // region lies in one (b,c) plane

  const f32x4* xv = (const f32x4*)x + base4;
  f32x4*       ov = (f32x4*)out + base4;
  const int t = threadIdx.x;

  f32x4 v0 = xv[t];
  f32x4 v1 = xv[t + 256];
  f32x4 v2 = xv[t + 512];
  f32x4 v3 = xv[t + 768];
#pragma unroll
  for (int it = 0; it < 4; ++it) {
    const int cur = t + it * 1024;
    f32x4 w0 = v0, w1 = v1, w2 = v2, w3 = v3;
    if (it < 3) {
      const int nxt = cur + 1024;
      v0 = xv[nxt];
      v1 = xv[nxt + 256];
      v2 = xv[nxt + 512];
      v3 = xv[nxt + 768];
    }
    w0 *= gg; w1 *= gg; w2 *= gg; w3 *= gg;
    __builtin_nontemporal_store(w0, &ov[cur]);
    __builtin_nontemporal_store(w1, &ov[cur + 256]);
    __builtin_nontemporal_store(w2, &ov[cur + 512]);
    __builtin_nontemporal_store(w3, &ov[cur + 768]);
  }
}

// ---------------------------------------------------------------------------
extern "C" void kernel_launch(void* const* d_in, const int* in_sizes, int n_in,
                              void* d_out, int out_size, void* d_ws, size_t ws_size,
                              hipStream_t stream) {
  const float* x    = (const float*)d_in[0];
  const float* Wrow = (const float*)d_in[1];
  const float* brow = (const float*)d_in[2];
  const float* W1   = (const float*)d_in[3];
  const float* b1   = (const float*)d_in[4];
  const float* W2   = (const float*)d_in[5];
  const float* b2   = (const float*)d_in[6];
  float* out = (float*)d_out;

  float* part = (float*)d_out;
  float* g    = (float*)d_ws;

  // ABLATION: gram launched twice (idempotent). dur_us - 153.9 == gram time.
  gram_pool_kernel<<<Bn * Sn, 256, 0, stream>>>(x, Wrow, part);
  gram_pool_kernel<<<Bn * Sn, 256, 0, stream>>>(x, Wrow, part);
  se_kernel<<<Bn, 64, 0, stream>>>(part, brow, W1, b1, W2, b2, g);
  scale_kernel<<<SGRID, 256, 0, stream>>>(x, g, out);
}

// Round 14
// 133.882 us; speedup vs baseline: 1.6314x; 1.6314x over previous
//
#include <hip/hip_runtime.h>
#include <math.h>

// Problem constants (from reference)
#define Bn   16
#define Cn   64
#define Nn   65536        // H*W = 256*256
#define Sn   64           // n-slices per batch for gram kernel
#define Ln   (Nn / Sn)    // 1024 k-elements per block
#define KT   64           // k per LDS tile
#define NT   (Ln / KT)    // 16 tiles
#define LW   68           // LDS row stride (floats): 16B-aligned, conflict-free
#define REDn 16

typedef float    f32x4  __attribute__((ext_vector_type(4)));
typedef float    f32x16 __attribute__((ext_vector_type(16)));
typedef __fp16   fp16x2 __attribute__((ext_vector_type(2)));
typedef _Float16 f16x8  __attribute__((ext_vector_type(8)));

union half8_u {
  f16x8  v;
  fp16x2 h[4];
};

// ---------------------------------------------------------------------------
// Kernel 1 (R14): block-staged k=64 double-buffered gram.
//  - staging loads are CONTIGUOUS 256B per row, 4 rows per wave-instr
//    (vs 16 scattered 64B rows before: the R13 ablation + R3->R5 trend says
//     the scattered pattern is what capped gram at 4.16 TB/s)
//  - raw s_barrier + counted vmcnt (compiler auto-emits vmcnt(8) for the
//    reg deps; NO vmcnt(0) drain in the main loop -> 8-12 loads stay in
//    flight across barriers, T3/T4 pattern)
//  - reg pipeline 3 tiles deep (sets indexed statically via full unroll)
// ---------------------------------------------------------------------------
__global__ __launch_bounds__(256, 4) void gram_pool_kernel(
    const float* __restrict__ x, const float* __restrict__ Wrow,
    float* __restrict__ part) {
  const int b    = blockIdx.x / Sn;
  const int s    = blockIdx.x % Sn;
  const int tid  = threadIdx.x;
  const int wid  = tid >> 6;
  const int lane = tid & 63;
  const int l31  = lane & 31;
  const int lhi  = lane >> 5;

  const float* xb = x + (size_t)b * Cn * Nn;

  __shared__ float buf[2][Cn * LW];     // two [64][68] f32 tiles (34.8 KB)
  __shared__ float pool_lds0[4][32];
  __shared__ float pool_lds1[4][32];

  // staging map: round i covers rows i*16+(tid>>4); 16 lanes/row -> 256B
  // contiguous per row, 4 rows per wave instruction.
  const float* gsrc[4];
  int wof[4];
#pragma unroll
  for (int i = 0; i < 4; ++i) {
    const int row = i * 16 + (tid >> 4);
    const int g   = tid & 15;                 // 16B granule within row
    gsrc[i] = xb + (size_t)row * Nn + g * 4;  // + k0 + t*KT per tile
    wof[i]  = row * LW + g * 4;
  }
  // fragment read offsets: lane row l31 / l31+32, cols wid*16+lhi*8 (+4)
  const int fA = l31 * LW + wid * 16 + lhi * 8;
  const int fB = (l31 + 32) * LW + wid * 16 + lhi * 8;

  const int k0 = s * Ln;

  f32x16 acc00, acc01, acc11;
#pragma unroll
  for (int r = 0; r < 16; ++r) { acc00[r] = 0.f; acc01[r] = 0.f; acc11[r] = 0.f; }
  float pool0 = 0.f, pool1 = 0.f;
  const fp16x2 one2 = {(__fp16)1.0f, (__fp16)1.0f};

  // ---- prologue: tiles 0,1,2 into reg sets 0,1,2; tile0 -> buf[0]
  f32x4 st[3][4];
#pragma unroll
  for (int q = 0; q < 3; ++q)
#pragma unroll
    for (int i = 0; i < 4; ++i)
      st[q][i] = *(const f32x4*)(gsrc[i] + k0 + q * KT);
#pragma unroll
  for (int i = 0; i < 4; ++i) *(f32x4*)&buf[0][wof[i]] = st[0][i];
  asm volatile("s_waitcnt lgkmcnt(0)" ::: "memory");
  __builtin_amdgcn_s_barrier();

  // ---- main loop: tile k lives in reg set k%3; buffer p = t&1
#pragma unroll
  for (int t = 0; t < NT; ++t) {
    const int p = t & 1;
    // a) issue loads for tile t+3 (set t%3 was freed by last iter's ds_write)
    if (t + 3 < NT) {
#pragma unroll
      for (int i = 0; i < 4; ++i)
        st[t % 3][i] = *(const f32x4*)(gsrc[i] + k0 + (t + 3) * KT);
    }
    // b) ds_write tile t+1 -> buf[p^1] (compiler auto-waits counted vmcnt)
    if (t + 1 < NT) {
#pragma unroll
      for (int i = 0; i < 4; ++i)
        *(f32x4*)&buf[p ^ 1][wof[i]] = st[(t + 1) % 3][i];
    }
    // c) compute this wave's k-16 slice of tile t from buf[p]
    {
      const float* wb = &buf[p][0];
      f32x4 a0 = *(const f32x4*)(wb + fA);
      f32x4 a1 = *(const f32x4*)(wb + fA + 4);
      f32x4 c0 = *(const f32x4*)(wb + fB);
      f32x4 c1 = *(const f32x4*)(wb + fB + 4);

      half8_u au, bu;
      au.h[0] = __builtin_amdgcn_cvt_pkrtz(a0[0], a0[1]);
      au.h[1] = __builtin_amdgcn_cvt_pkrtz(a0[2], a0[3]);
      au.h[2] = __builtin_amdgcn_cvt_pkrtz(a1[0], a1[1]);
      au.h[3] = __builtin_amdgcn_cvt_pkrtz(a1[2], a1[3]);
      bu.h[0] = __builtin_amdgcn_cvt_pkrtz(c0[0], c0[1]);
      bu.h[1] = __builtin_amdgcn_cvt_pkrtz(c0[2], c0[3]);
      bu.h[2] = __builtin_amdgcn_cvt_pkrtz(c1[0], c1[1]);
      bu.h[3] = __builtin_amdgcn_cvt_pkrtz(c1[2], c1[3]);

#pragma unroll
      for (int i = 0; i < 4; ++i) {
        pool0 = __builtin_amdgcn_fdot2(au.h[i], one2, pool0, false);
        pool1 = __builtin_amdgcn_fdot2(bu.h[i], one2, pool1, false);
      }

      acc00 = __builtin_amdgcn_mfma_f32_32x32x16_f16(au.v, au.v, acc00, 0, 0, 0);
      acc01 = __builtin_amdgcn_mfma_f32_32x32x16_f16(au.v, bu.v, acc01, 0, 0, 0);
      acc11 = __builtin_amdgcn_mfma_f32_32x32x16_f16(bu.v, bu.v, acc11, 0, 0, 0);
    }
    // d) make ds_writes visible, then raw barrier (no vmcnt drain)
    asm volatile("s_waitcnt lgkmcnt(0)" ::: "memory");
    __builtin_amdgcn_s_barrier();
  }

  // ---- pool reduce
  pool0 += __shfl_down(pool0, 32);
  pool1 += __shfl_down(pool1, 32);
  if (lane < 32) {
    pool_lds0[wid][lane] = pool0;
    pool_lds1[wid][lane] = pool1;
  }

  // ---- corr accumulation: overlay [64][65] on buf[0] (dead after loop)
  float (*corr)[Cn + 1] = (float(*)[Cn + 1])&buf[0][0];   // 16.6KB <= 17.4KB
  for (int w = 0; w < 4; ++w) {
    __syncthreads();
    if (wid == w) {
#pragma unroll
      for (int r = 0; r < 16; ++r) {
        // verified C/D layout (32x32 MFMA): col=lane&31, row=(r&3)+8*(r>>2)+4*(lane>>5)
        const int i = (r & 3) + 8 * (r >> 2) + 4 * lhi;
        const int j = l31;
        if (w == 0) {
          corr[i][j]           = acc00[r];
          corr[i][j + 32]      = acc01[r];
          corr[j + 32][i]      = acc01[r];   // symmetric mirror
          corr[i + 32][j + 32] = acc11[r];
        } else {
          corr[i][j]           += acc00[r];
          corr[i][j + 32]      += acc01[r];
          corr[j + 32][i]      += acc01[r];
          corr[i + 32][j + 32] += acc11[r];
        }
      }
    }
  }
  __syncthreads();

  if (tid < Cn) {
    const float* wr = Wrow + tid * Cn;
    float so = 0.f;
#pragma unroll 8
    for (int d = 0; d < Cn; ++d) so += corr[tid][d] * wr[d];
    float pp = 0.f;
    if (tid < 32) {
#pragma unroll
      for (int w = 0; w < 4; ++w) pp += pool_lds0[w][tid];
    } else {
#pragma unroll
      for (int w = 0; w < 4; ++w) pp += pool_lds1[w][tid - 32];
    }
    float* o = part + (size_t)(b * Sn + s) * (2 * Cn);
    o[tid]      = so;
    o[Cn + tid] = pp;
  }
}

// ---------------------------------------------------------------------------
// Kernel 2: per-batch reduce partials + tiny MLP -> gate g[b,c]
// ---------------------------------------------------------------------------
__global__ __launch_bounds__(64) void se_kernel(
    const float* __restrict__ part, const float* __restrict__ brow,
    const float* __restrict__ W1, const float* __restrict__ b1,
    const float* __restrict__ W2, const float* __restrict__ b2,
    float* __restrict__ g) {
  const int b = blockIdx.x;
  const int t = threadIdx.x;   // 0..63

  __shared__ float y_s[Cn];
  __shared__ float z_s[REDn];

  float so = 0.f, pl = 0.f;
  for (int s = 0; s < Sn; ++s) {
    const float* p = part + (size_t)(b * Sn + s) * (2 * Cn);
    so += p[t];
    pl += p[Cn + t];
  }
  y_s[t] = (so + pl) * (1.0f / (float)Nn) + brow[t];
  __syncthreads();

  if (t < REDn) {
    float z = b1[t];
#pragma unroll 8
    for (int c = 0; c < Cn; ++c) z += W1[t * Cn + c] * y_s[c];
    z_s[t] = fmaxf(z, 0.f);
  }
  __syncthreads();

  float a = b2[t];
#pragma unroll
  for (int r = 0; r < REDn; ++r) a += W2[t * REDn + r] * z_s[r];
  g[b * Cn + t] = 1.0f / (1.0f + expf(-a));
}

// ---------------------------------------------------------------------------
// Kernel 3: out[b,c,n] = x[b,c,n] * g[b,c]  (contiguous per-plane blocks, NT)
// At the copy ceiling per R13 ablation (~6.7 TB/s effective) -- unchanged.
// ---------------------------------------------------------------------------
#define SGRID 4096        // 16384 float4 per (b,c) / 4096 per block = 4 blocks/plane
__global__ __launch_bounds__(256) void scale_kernel(
    const float* __restrict__ x, const float* __restrict__ g,
    float* __restrict__ out) {
  const int    bid   = blockIdx.x;
  const size_t base4 = (size_t)bid * 4096;   // float4 index of block's region
  const float  gg    = g[bid >> 2];          // region lies in one (b,c) plane

  const f32x4* xv = (const f32x4*)x + base4;
  f32x4*       ov = (f32x4*)out + base4;
  const int t = threadIdx.x;

  f32x4 v0 = xv[t];
  f32x4 v1 = xv[t + 256];
  f32x4 v2 = xv[t + 512];
  f32x4 v3 = xv[t + 768];
#pragma unroll
  for (int it = 0; it < 4; ++it) {
    const int cur = t + it * 1024;
    f32x4 w0 = v0, w1 = v1, w2 = v2, w3 = v3;
    if (it < 3) {
      const int nxt = cur + 1024;
      v0 = xv[nxt];
      v1 = xv[nxt + 256];
      v2 = xv[nxt + 512];
      v3 = xv[nxt + 768];
    }
    w0 *= gg; w1 *= gg; w2 *= gg; w3 *= gg;
    __builtin_nontemporal_store(w0, &ov[cur]);
    __builtin_nontemporal_store(w1, &ov[cur + 256]);
    __builtin_nontemporal_store(w2, &ov[cur + 512]);
    __builtin_nontemporal_store(w3, &ov[cur + 768]);
  }
}

// ---------------------------------------------------------------------------
extern "C" void kernel_launch(void* const* d_in, const int* in_sizes, int n_in,
                              void* d_out, int out_size, void* d_ws, size_t ws_size,
                              hipStream_t stream) {
  const float* x    = (const float*)d_in[0];
  const float* Wrow = (const float*)d_in[1];
  const float* brow = (const float*)d_in[2];
  const float* W1   = (const float*)d_in[3];
  const float* b1   = (const float*)d_in[4];
  const float* W2   = (const float*)d_in[5];
  const float* b2   = (const float*)d_in[6];
  float* out = (float*)d_out;

  float* part = (float*)d_out;   // partials in front of d_out (overwritten)
  float* g    = (float*)d_ws;    // gate (4 KB)

  gram_pool_kernel<<<Bn * Sn, 256, 0, stream>>>(x, Wrow, part);
  se_kernel<<<Bn, 64, 0, stream>>>(part, brow, W1, b1, W2, b2, g);
  scale_kernel<<<SGRID, 256, 0, stream>>>(x, g, out);
}